// Round 8
// baseline (5747.605 us; speedup 1.0000x reference)
//
#include <hip/hip_runtime.h>

#define HIDN 150
#define NG   600     // 4*HIDN gates
#define NGP  640     // padded gate width / G row stride / slot count
#define TT   512
#define NBATCH 256
#define KPA  160     // padded K for H->next-layer A buffers (also scan k-pad)
#define KPE  320     // padded K for embedding
#define WPT  200     // scan weights per thread (50 float4)

typedef __attribute__((ext_vector_type(8))) short bf16x8;
typedef __attribute__((ext_vector_type(4))) float f32x4;

__device__ __forceinline__ unsigned short f2bf(float v) {
    unsigned int u = __builtin_bit_cast(unsigned int, v);
    u += 0x7fffu + ((u >> 16) & 1u);          // RNE
    return (unsigned short)(u >> 16);
}
__device__ __forceinline__ float bf2f(unsigned short h) {
    unsigned int u = ((unsigned int)h) << 16;
    return __builtin_bit_cast(float, u);
}

#define GLDS(gp, lp) __builtin_amdgcn_global_load_lds( \
    (const __attribute__((address_space(1))) unsigned int*)(gp), \
    (__attribute__((address_space(3))) unsigned int*)(lp), 16, 0, 0)

// slot for gate column n (n<600): g=n/150, u=n%150.
// u<128: s = u + 128*g  (gates of u live in quad u)
// u>=128: s = 512 + 4*(u-128) + g  (overflow block, quad 4*(u-128)+g)
__device__ __forceinline__ int slot_of(int n) {
    int g = n / HIDN, u = n - g * HIDN;
    return (u < 128) ? (u + (g << 7)) : (512 + 4 * (u - 128) + g);
}

// ---------------- embedding split: emb[50000][300] fp32 -> embh/embl [50000][320] bf16 ----------------
__global__ __launch_bounds__(256) void embprep_kernel(
    const float* __restrict__ emb,
    unsigned short* __restrict__ eh, unsigned short* __restrict__ el)
{
    int i = blockIdx.x * 256 + threadIdx.x;
    if (i >= 50000 * KPE) return;
    int v = i / KPE, k = i - v * KPE;
    float x = (k < 300) ? emb[(size_t)v * 300 + k] : 0.f;
    unsigned short hi = f2bf(x);
    eh[i] = hi;
    el[i] = f2bf(x - bf2f(hi));
}

// ---------------- per-layer weight prep ----------------
// Wgh/Wgl: [640][Kp] bf16 hi/lo of Wih (gemm B^T).
// Wt2: [512][200] fp32 per-scan-thread weights:
//   thread t (q=t&3, c0=t>>2), entry o = j*40+r  ->  Whh[n(slot c0+128j)][q*40+r]
// bsum: [640] fp32 bih+bhh (natural col order, gemm epilogue).
__global__ __launch_bounds__(256) void prep_kernel(
    const float* __restrict__ Wih, const float* __restrict__ Whh,
    const float* __restrict__ bih, const float* __restrict__ bhh,
    int K, int Kp,
    unsigned short* __restrict__ Wgh, unsigned short* __restrict__ Wgl,
    float* __restrict__ Wt2, float* __restrict__ bsum)
{
    int i = blockIdx.x * 256 + threadIdx.x;
    int nW = NGP * Kp;
    if (i < nW) {
        int n = i / Kp, k = i - n * Kp;
        float w = (n < NG && k < K) ? Wih[(size_t)n * K + k] : 0.f;
        unsigned short hi = f2bf(w);
        Wgh[i] = hi;
        Wgl[i] = f2bf(w - bf2f(hi));
    } else if (i < nW + 512 * WPT) {
        int j2 = i - nW;
        int t = j2 / WPT, o = j2 - t * WPT;
        int jj = o / 40, r = o - jj * 40;
        int q = t & 3, c0 = t >> 2;
        int k = q * 40 + r;
        float w = 0.f;
        if (k < HIDN) {
            int u = -1, g = 0;
            if (jj < 4) { u = c0; g = jj; }                       // mainstream (c0<128 always)
            else if (c0 < 88) { u = 128 + (c0 >> 2); g = c0 & 3; } // overflow
            if (u >= 0) w = Whh[(size_t)(g * HIDN + u) * HIDN + k];
        }
        Wt2[j2] = w;
    } else if (i < nW + 512 * WPT + NGP) {
        int g = i - nW - 512 * WPT;
        bsum[g] = (g < NG) ? (bih[g] + bhh[g]) : 0.f;
    }
}

// ---------------- x_proj GEMM: split-bf16 MFMA ----------------
// G written in slot order, row stride 640.
__global__ __launch_bounds__(256, 2) void gemm_kernel(
    const unsigned short* __restrict__ Ah, const unsigned short* __restrict__ Al,
    const int* __restrict__ gather,
    const unsigned short* __restrict__ Eh, const unsigned short* __restrict__ El,
    int Kp,
    const unsigned short* __restrict__ Wh, const unsigned short* __restrict__ Wl,
    const float* __restrict__ bsum, const int* __restrict__ lengths,
    float* __restrict__ G,                                       // [NBc*Tc][640] slot order
    int b_off, int t0, int lTc)
{
    int m0 = blockIdx.x * 128;
    int n0 = blockIdx.y * 128;
    int Tcm1 = (1 << lTc) - 1;
    if (lTc >= 7) {
        int b = b_off + (m0 >> lTc);
        if (t0 + (m0 & Tcm1) >= lengths[b]) return;
    }

    __shared__ __align__(16) unsigned short Ash[128][32];
    __shared__ __align__(16) unsigned short Asl[128][32];
    __shared__ __align__(16) unsigned short Bsh[128][32];
    __shared__ __align__(16) unsigned short Bsl[128][32];

    int tid = threadIdx.x, lane = tid & 63, wave = tid >> 6;

    const unsigned short* AhB = gather ? Eh : Ah;
    const unsigned short* AlB = gather ? El : Al;
    size_t ra[2], rb[2];
    int mrow[2];
    #pragma unroll
    for (int c2 = 0; c2 < 2; ++c2) {
        int mb = wave * 32 + c2 * 16;
        mrow[c2] = mb;
        int rg = m0 + mb + (lane >> 2);
        int bb = rg >> lTc, tl = rg & Tcm1;
        ra[c2] = gather ? (size_t)gather[(b_off + bb) * TT + t0 + tl] * (size_t)Kp
                        : ((size_t)bb * TT + t0 + tl) * (size_t)Kp;
        int nr = n0 + mb + (lane >> 2);
        rb[c2] = (size_t)nr * (size_t)Kp;
    }
    int klane = (lane & 3) * 8;

    f32x4 acc[4][4];
    #pragma unroll
    for (int i = 0; i < 4; ++i)
        #pragma unroll
        for (int j = 0; j < 4; ++j) acc[i][j] = (f32x4){0.f, 0.f, 0.f, 0.f};

    int fr = (lane >> 4) * 8;
    int ml = lane & 15;
    int mbase = (wave & 1) * 64;
    int nbase = (wave >> 1) * 64;

    for (int k0 = 0; k0 < Kp; k0 += 32) {
        #pragma unroll
        for (int c2 = 0; c2 < 2; ++c2) {
            GLDS(AhB + ra[c2] + k0 + klane, &Ash[mrow[c2]][0]);
            GLDS(AlB + ra[c2] + k0 + klane, &Asl[mrow[c2]][0]);
            GLDS(Wh  + rb[c2] + k0 + klane, &Bsh[mrow[c2]][0]);
            GLDS(Wl  + rb[c2] + k0 + klane, &Bsl[mrow[c2]][0]);
        }
        __syncthreads();

        bf16x8 afh[4], afl[4], bfh[4], bfl[4];
        #pragma unroll
        for (int i = 0; i < 4; ++i) {
            afh[i] = *(const bf16x8*)&Ash[mbase + i * 16 + ml][fr];
            afl[i] = *(const bf16x8*)&Asl[mbase + i * 16 + ml][fr];
            bfh[i] = *(const bf16x8*)&Bsh[nbase + i * 16 + ml][fr];
            bfl[i] = *(const bf16x8*)&Bsl[nbase + i * 16 + ml][fr];
        }
        #pragma unroll
        for (int i = 0; i < 4; ++i)
            #pragma unroll
            for (int j = 0; j < 4; ++j)
                acc[i][j] = __builtin_amdgcn_mfma_f32_16x16x32_bf16(afh[i], bfh[j], acc[i][j], 0, 0, 0);
        #pragma unroll
        for (int i = 0; i < 4; ++i)
            #pragma unroll
            for (int j = 0; j < 4; ++j)
                acc[i][j] = __builtin_amdgcn_mfma_f32_16x16x32_bf16(afh[i], bfl[j], acc[i][j], 0, 0, 0);
        #pragma unroll
        for (int i = 0; i < 4; ++i)
            #pragma unroll
            for (int j = 0; j < 4; ++j)
                acc[i][j] = __builtin_amdgcn_mfma_f32_16x16x32_bf16(afl[i], bfh[j], acc[i][j], 0, 0, 0);
        __syncthreads();
    }

    int rq = lane >> 4;
    #pragma unroll
    for (int i = 0; i < 4; ++i) {
        int mg = m0 + mbase + i * 16 + rq * 4;
        #pragma unroll
        for (int j = 0; j < 4; ++j) {
            int ng = n0 + nbase + j * 16 + ml;
            if (ng < NG) {
                float bz = bsum[ng];
                int s = slot_of(ng);
                #pragma unroll
                for (int r = 0; r < 4; ++r)
                    G[(size_t)(mg + r) * NGP + s] = acc[i][j][r] + bz;
            }
        }
    }
}

// ---------------- recurrent scan: 512 threads, quarter-split dot, weights in VGPRs ----------------
// thread t (q=t&3, c0=t>>2): 5 quarter-dots (40 k-rows each) for slots {c0+128j}.
// Quad butterfly (shfl_xor 1,2) completes each slot's dot. Gates of unit u<128 are
// slots u+128g -> all in quad u -> cell update in-quad with zero exchange.
// Overflow units 128..149 at slots 512+4w+g -> 3 intra-wave shuffles.
__global__ __launch_bounds__(512, 2) void scan_kernel(
    const float* __restrict__ G,        // [NBc][Tc][640] slot order
    const float* __restrict__ Wt2,      // [512][200] per-thread weights
    const int*   __restrict__ lengths,
    unsigned short* __restrict__ Aout,  // [NBc][512][160] bf16-hi h, or null (layer 3)
    unsigned short* __restrict__ Alout,
    float* __restrict__ hnb,            // [256][150]
    float* __restrict__ hst, float* __restrict__ cst,   // [NBc][160] carries
    int b_off, int t0, int Tc)
{
    __shared__ __align__(16) float h_s[2][160];
    __shared__ __align__(16) float Gs[2][NGP];

    int tid = threadIdx.x;
    int q = tid & 3, c0 = tid >> 2;
    bool leadM = (q == 0);                      // cell owner for u0=c0 (<128)
    bool leadO = ((tid & 15) == 0) && ((tid >> 4) < 22);
    int w_ov = tid >> 4;                        // overflow unit 128+w_ov
    int L = tid & 63;

    int l0 = blockIdx.x, b = b_off + l0;
    int len = lengths[b];
    int tmax = min(len, t0 + Tc);

    // one-time weight residency: 50 float4 = 200 VGPRs
    float4 wreg[50];
    {
        const float4* wp = (const float4*)(Wt2 + (size_t)tid * WPT);
        #pragma unroll
        for (int i = 0; i < 50; ++i) wreg[i] = wp[i];
    }

    if (tid < 160) {
        float hv = (t0 > 0 && tid < HIDN) ? hst[l0 * 160 + tid] : 0.f;
        h_s[0][tid] = hv;
        h_s[1][tid] = hv;        // pad rows 150..159 stay 0 forever
    }
    float cM = 0.f, cO = 0.f;
    if (t0 > 0) {
        if (leadM) cM = cst[l0 * 160 + c0];
        if (leadO) cO = cst[l0 * 160 + 128 + w_ov];
    }

    const float* Grow = G + (size_t)l0 * Tc * NGP;
    float g1n = 0.f, g2n = 0.f;
    if (t0 < tmax) {
        // stage G[t0] and prefetch G[t0+1]
        g1n = Grow[tid];
        if (tid < 128) g2n = Grow[512 + tid];
        Gs[0][tid] = g1n;
        if (tid < 128) Gs[0][512 + tid] = g2n;
        int tl1 = (1 < tmax - t0) ? 1 : 0;
        g1n = Grow[(size_t)tl1 * NGP + tid];
        if (tid < 128) g2n = Grow[(size_t)tl1 * NGP + 512 + tid];
    }
    __syncthreads();

    int p = 0;
    int hbase = q * 40;
    for (int t = t0; t < tmax; ++t) {
        int buf = (t - t0) & 1;
        const float* hp = h_s[p];
        float s0 = 0.f, s1 = 0.f, s2 = 0.f, s3 = 0.f, s4 = 0.f;
        #pragma unroll
        for (int i = 0; i < 10; ++i) {
            float4 h4 = *(const float4*)&hp[hbase + 4 * i];
            float4 w0 = wreg[i], w1 = wreg[10 + i], w2 = wreg[20 + i];
            float4 w3 = wreg[30 + i], w4 = wreg[40 + i];
            s0 += w0.x * h4.x + w0.y * h4.y + w0.z * h4.z + w0.w * h4.w;
            s1 += w1.x * h4.x + w1.y * h4.y + w1.z * h4.z + w1.w * h4.w;
            s2 += w2.x * h4.x + w2.y * h4.y + w2.z * h4.z + w2.w * h4.w;
            s3 += w3.x * h4.x + w3.y * h4.y + w3.z * h4.z + w3.w * h4.w;
            s4 += w4.x * h4.x + w4.y * h4.y + w4.z * h4.z + w4.w * h4.w;
        }
        if (leadM) {                      // fold G in exactly once per slot
            s0 += Gs[buf][c0];
            s1 += Gs[buf][c0 + 128];
            s2 += Gs[buf][c0 + 256];
            s3 += Gs[buf][c0 + 384];
            s4 += Gs[buf][c0 + 512];
        }
        // quad butterfly: every lane of the quad ends with the full slot sums
        s0 += __shfl_xor(s0, 1); s0 += __shfl_xor(s0, 2);
        s1 += __shfl_xor(s1, 1); s1 += __shfl_xor(s1, 2);
        s2 += __shfl_xor(s2, 1); s2 += __shfl_xor(s2, 2);
        s3 += __shfl_xor(s3, 1); s3 += __shfl_xor(s3, 2);
        s4 += __shfl_xor(s4, 1); s4 += __shfl_xor(s4, 2);
        // overflow gate gather (f,g,o gates live 4/8/12 lanes up)
        float og1 = __shfl(s4, L + 4);
        float og2 = __shfl(s4, L + 8);
        float og3 = __shfl(s4, L + 12);

        if (leadM) {
            float iv = 1.f / (1.f + __expf(-s0));
            float fv = 1.f / (1.f + __expf(-s1));
            float gv = 2.f / (1.f + __expf(-2.f * s2)) - 1.f;
            float ov = 1.f / (1.f + __expf(-s3));
            float cn = fv * cM + iv * gv;
            float th = 2.f / (1.f + __expf(-2.f * cn)) - 1.f;
            float hv = ov * th;
            cM = cn;
            h_s[p ^ 1][c0] = hv;
            if (Aout) {
                size_t off = ((size_t)l0 * TT + t) * KPA + c0;
                unsigned short hi = f2bf(hv);
                Aout[off] = hi;
                Alout[off] = f2bf(hv - bf2f(hi));
            }
            if (t == len - 1) hnb[b * HIDN + c0] = hv;
        }
        if (leadO) {
            float iv = 1.f / (1.f + __expf(-s4));
            float fv = 1.f / (1.f + __expf(-og1));
            float gv = 2.f / (1.f + __expf(-2.f * og2)) - 1.f;
            float ov = 1.f / (1.f + __expf(-og3));
            float cn = fv * cO + iv * gv;
            float th = 2.f / (1.f + __expf(-2.f * cn)) - 1.f;
            float hv = ov * th;
            cO = cn;
            int u = 128 + w_ov;
            h_s[p ^ 1][u] = hv;
            if (Aout) {
                size_t off = ((size_t)l0 * TT + t) * KPA + u;
                unsigned short hi = f2bf(hv);
                Aout[off] = hi;
                Alout[off] = f2bf(hv - bf2f(hi));
            }
            if (t == len - 1) hnb[b * HIDN + u] = hv;
        }

        // stage G[t+1] into other buffer; prefetch G[t+2]
        Gs[buf ^ 1][tid] = g1n;
        if (tid < 128) Gs[buf ^ 1][512 + tid] = g2n;
        {
            int tl2 = t + 2 - t0;
            int cap = tmax - 1 - t0;
            if (tl2 > cap) tl2 = cap;
            g1n = Grow[(size_t)tl2 * NGP + tid];
            if (tid < 128) g2n = Grow[(size_t)tl2 * NGP + 512 + tid];
        }
        __syncthreads();
        p ^= 1;
    }

    if (tid < 160) hst[l0 * 160 + tid] = h_s[p][tid];
    if (leadM) cst[l0 * 160 + c0] = cM;
    if (leadO) cst[l0 * 160 + 128 + w_ov] = cO;
}

// ---------------- fc1+relu+fc2 head ----------------
__global__ __launch_bounds__(256) void head_kernel(
    const float* __restrict__ hnb, const float* __restrict__ fc1_w,
    const float* __restrict__ fc1_b, const float* __restrict__ fc2_w,
    const float* __restrict__ fc2_b, float* __restrict__ out)
{
    __shared__ float hs[HIDN];
    __shared__ float zs[HIDN];
    int b = blockIdx.x, tid = threadIdx.x;
    if (tid < HIDN) hs[tid] = hnb[b * HIDN + tid];
    __syncthreads();
    if (tid < HIDN) {
        float acc = fc1_b[tid];
        const float* wr = fc1_w + (size_t)tid * HIDN;
        #pragma unroll 5
        for (int k = 0; k < HIDN; ++k) acc += wr[k] * hs[k];
        zs[tid] = fmaxf(acc, 0.f);
    }
    __syncthreads();
    if (tid == 0) {
        float s = fc2_b[0];
        for (int k = 0; k < HIDN; ++k) s += fc2_w[k] * zs[k];
        out[b] = s;
    }
}

extern "C" void kernel_launch(void* const* d_in, const int* in_sizes, int n_in,
                              void* d_out, int out_size, void* d_ws, size_t ws_size,
                              hipStream_t stream)
{
    const int*   x       = (const int*)d_in[0];
    const int*   lengths = (const int*)d_in[1];
    const float* emb     = (const float*)d_in[2];
    const float *Wih[4], *Whh[4], *bih[4], *bhh[4];
    for (int l = 0; l < 4; ++l) {
        Wih[l] = (const float*)d_in[3 + 4 * l];
        Whh[l] = (const float*)d_in[4 + 4 * l];
        bih[l] = (const float*)d_in[5 + 4 * l];
        bhh[l] = (const float*)d_in[6 + 4 * l];
    }
    const float* fc1_w = (const float*)d_in[19];
    const float* fc1_b = (const float*)d_in[20];
    const float* fc2_w = (const float*)d_in[21];
    const float* fc2_b = (const float*)d_in[22];

    int Kl[4]  = {300, 150, 150, 150};
    int Kp[4]  = {KPE, KPA, KPA, KPA};
    size_t wgoff[4];
    size_t wgacc = 0;
    for (int l = 0; l < 4; ++l) { wgoff[l] = wgacc; wgacc += 2 * (size_t)NGP * Kp[l]; }
    const int WT2_STRIDE = 512 * WPT;                // 102400 floats per layer

    // ---- adaptive workspace sizing ----
    size_t wf = ws_size / sizeof(float);
    const size_t WFIX = (size_t)4 * WT2_STRIDE + 2560 + 38400 + 512000 + 16000000;
    int NBc = 0, Tc = 0;
    for (int nb = 256; nb >= 16; nb >>= 1) {
        for (int tc = 512; tc >= 8; tc >>= 1) {
            size_t need = WFIX + (size_t)nb * 320                 // h/c carry (stride 160)
                        + (size_t)nb * TT * KPA                   // Ah+Al (2 ushort bufs)
                        + (size_t)nb * tc * NGP;                  // G chunk
            if (need <= wf) { NBc = nb; Tc = tc; break; }
        }
        if (NBc) break;
    }
    if (!NBc) return;
    int lTc = __builtin_ctz(Tc);

    float* ws  = (float*)d_ws;
    float* Wt2 = ws;                                    // 4 * 102400
    float* bsm = Wt2 + 4 * WT2_STRIDE;                  // 4 * 640
    float* hnb = bsm + 2560;                            // 256*150
    unsigned short* Wg = (unsigned short*)(hnb + 38400);        // 1,024,000 ushorts
    unsigned short* embh = Wg + 1024000;                        // 16,000,000 ushorts
    unsigned short* embl = embh + 16000000;                     // 16,000,000 ushorts
    float* hst = (float*)(embl + 16000000);             // NBc*160
    float* cst = hst + (size_t)NBc * 160;               // NBc*160
    unsigned short* Ahh = (unsigned short*)(cst + (size_t)NBc * 160);   // NBc*512*160
    unsigned short* Ahl = Ahh + (size_t)NBc * TT * KPA;                 // NBc*512*160
    float* G   = (float*)(Ahl + (size_t)NBc * TT * KPA);                // NBc*Tc*640

    embprep_kernel<<<(50000 * KPE + 255) / 256, 256, 0, stream>>>(emb, embh, embl);
    for (int l = 0; l < 4; ++l) {
        int total = NGP * Kp[l] + 512 * WPT + NGP;
        prep_kernel<<<(total + 255) / 256, 256, 0, stream>>>(
            Wih[l], Whh[l], bih[l], bhh[l], Kl[l], Kp[l],
            Wg + wgoff[l], Wg + wgoff[l] + (size_t)NGP * Kp[l],
            Wt2 + (size_t)l * WT2_STRIDE, bsm + l * 640);
    }

    int nTc = TT / Tc;
    int nBc = NBATCH / NBc;
    dim3 ggrid((unsigned)(NBc * Tc / 128), 5);
    for (int bc = 0; bc < nBc; ++bc) {
        int b_off = bc * NBc;
        for (int l = 0; l < 4; ++l) {
            const unsigned short* Wh = Wg + wgoff[l];
            const unsigned short* Wl = Wh + (size_t)NGP * Kp[l];
            for (int tc = 0; tc < nTc; ++tc) {
                int t0 = tc * Tc;
                gemm_kernel<<<ggrid, 256, 0, stream>>>(
                    (l == 0) ? nullptr : Ahh, (l == 0) ? nullptr : Ahl,
                    (l == 0) ? x : nullptr, embh, embl,
                    Kp[l], Wh, Wl, bsm + l * 640, lengths, G, b_off, t0, lTc);
                scan_kernel<<<NBc, 512, 0, stream>>>(
                    G, Wt2 + (size_t)l * WT2_STRIDE, lengths,
                    (l == 3) ? nullptr : Ahh, (l == 3) ? nullptr : Ahl,
                    hnb, hst, cst, b_off, t0, Tc);
            }
        }
    }
    head_kernel<<<256, 256, 0, stream>>>(hnb, fc1_w, fc1_b, fc2_w, fc2_b, (float*)d_out);
}